// Round 1
// baseline (878.352 us; speedup 1.0000x reference)
//
#include <hip/hip_runtime.h>
#include <math.h>

#define D      32000
#define BNUM   64
#define KNUM   4096
#define DSPLIT 4
#define DPER   (D / DSPLIT)   // 8000
#define BK     64             // d-chunk per LDS stage
#define NK     32             // codebook rows per block
#define KBLKS  (KNUM / NK)    // 128
#define STRIDE 68             // BK + 4 floats pad (keeps 16B align, breaks b-stride conflicts)

// ---------------------------------------------------------------------------
// Kernel 1: partial xc[b][k] over one D-split + fused ||c||^2 accumulation.
// Block: 256 threads = (bg 0..7) x (kg 0..3) x (ds 0..7).
// Thread tile: 8 b x 8 k, 4 consecutive d per inner step.
// ---------------------------------------------------------------------------
__global__ __launch_bounds__(256) void dist_gemm(
    const float* __restrict__ latent, const float* __restrict__ codebook,
    float* __restrict__ ws_xc, float* __restrict__ ws_c2)
{
    __shared__ __align__(16) float xs[BNUM * STRIDE];  // 64 x 68
    __shared__ __align__(16) float cs[NK * STRIDE];    // 32 x 68

    const int tid = threadIdx.x;
    const int ds  = tid & 7;
    const int kg  = (tid >> 3) & 3;
    const int bg  = tid >> 5;
    const int k0  = blockIdx.x * NK;
    const int d0b = blockIdx.y * DPER;

    float acc[8][8];
#pragma unroll
    for (int i = 0; i < 8; i++)
#pragma unroll
        for (int j = 0; j < 8; j++) acc[i][j] = 0.f;
    float c2a[8] = {0.f, 0.f, 0.f, 0.f, 0.f, 0.f, 0.f, 0.f};

    // staging coords
    const int xr = tid >> 2, xc4 = tid & 3;   // latent: 64 rows, 4 loaders/row
    const int cr = tid >> 3, cc8 = tid & 7;   // codebook: 32 rows, 8 loaders/row

    for (int d0 = d0b; d0 < d0b + DPER; d0 += BK) {
        __syncthreads();
        // stage latent chunk [64][BK]
#pragma unroll
        for (int q = 0; q < 4; q++) {
            const int col = (q * 4 + xc4) * 4;
            const float4 v = *(const float4*)(latent + (size_t)xr * D + d0 + col);
            *(float4*)(xs + xr * STRIDE + col) = v;
        }
        // stage codebook chunk [32][BK]
#pragma unroll
        for (int q = 0; q < 2; q++) {
            const int col = (q * 8 + cc8) * 4;
            const float4 v = *(const float4*)(codebook + (size_t)(k0 + cr) * D + d0 + col);
            *(float4*)(cs + cr * STRIDE + col) = v;
        }
        __syncthreads();

#pragma unroll
        for (int t = 0; t < 2; t++) {
            const int dd = 4 * ds + 32 * t;
            float4 cv[8];
#pragma unroll
            for (int j = 0; j < 8; j++)
                cv[j] = *(const float4*)(cs + (kg * 8 + j) * STRIDE + dd);
            if (bg == 0) {  // fused ||c||^2 (wave-0 low half only; no redundancy)
#pragma unroll
                for (int j = 0; j < 8; j++)
                    c2a[j] += cv[j].x * cv[j].x + cv[j].y * cv[j].y +
                              cv[j].z * cv[j].z + cv[j].w * cv[j].w;
            }
#pragma unroll
            for (int i = 0; i < 8; i++) {
                const float4 xv = *(const float4*)(xs + (bg * 8 + i) * STRIDE + dd);
#pragma unroll
                for (int j = 0; j < 8; j++) {
                    acc[i][j] += xv.x * cv[j].x + xv.y * cv[j].y +
                                 xv.z * cv[j].z + xv.w * cv[j].w;
                }
            }
        }
    }

    // reduce over the 8 ds lanes (tid = ...|ds in low 3 bits -> same wave, 8-aligned)
#pragma unroll
    for (int i = 0; i < 8; i++)
#pragma unroll
        for (int j = 0; j < 8; j++) {
            float v = acc[i][j];
            v += __shfl_xor(v, 1);
            v += __shfl_xor(v, 2);
            v += __shfl_xor(v, 4);
            acc[i][j] = v;
        }
    if (ds == 0) {
#pragma unroll
        for (int i = 0; i < 8; i++) {
            float4 w0, w1;
            w0.x = acc[i][0]; w0.y = acc[i][1]; w0.z = acc[i][2]; w0.w = acc[i][3];
            w1.x = acc[i][4]; w1.y = acc[i][5]; w1.z = acc[i][6]; w1.w = acc[i][7];
            const size_t off = ((size_t)blockIdx.y * BNUM + bg * 8 + i) * KNUM + k0 + kg * 8;
            *(float4*)(ws_xc + off)     = w0;
            *(float4*)(ws_xc + off + 4) = w1;
        }
    }
    if (bg == 0) {
#pragma unroll
        for (int j = 0; j < 8; j++) {
            float v = c2a[j];
            v += __shfl_xor(v, 1);
            v += __shfl_xor(v, 2);
            v += __shfl_xor(v, 4);
            if (ds == 0) atomicAdd(ws_c2 + k0 + kg * 8 + j, v);
        }
    }
}

// ---------------------------------------------------------------------------
// Kernel 2: per-b argmin over k, min distance, index outputs, usage copy.
// score(k) = c2[k] - 2*xc  (x2 added only for the final distance value)
// ---------------------------------------------------------------------------
__global__ __launch_bounds__(256) void argmin_k(
    const float* __restrict__ latent, const float* __restrict__ ws_xc,
    const float* __restrict__ ws_c2, const float* __restrict__ usage_in,
    float* __restrict__ out_idx, float* __restrict__ out_mind,
    float* __restrict__ out_usage, int* __restrict__ ws_idx)
{
    const int b = blockIdx.x, tid = threadIdx.x;
    __shared__ float svals[256];
    __shared__ int   sidx[256];

    // ||x_b||^2
    float s = 0.f;
    const float4* lf4 = (const float4*)(latent + (size_t)b * D);
    for (int i = tid; i < D / 4; i += 256) {
        const float4 v = lf4[i];
        s += v.x * v.x + v.y * v.y + v.z * v.z + v.w * v.w;
    }
    svals[tid] = s;
    __syncthreads();
    for (int off = 128; off > 0; off >>= 1) {
        if (tid < off) svals[tid] += svals[tid + off];
        __syncthreads();
    }
    const float x2 = svals[0];
    __syncthreads();

    // scan k
    float best = 3.402823466e38f;
    int   bi   = 0;
    for (int k = tid; k < KNUM; k += 256) {
        float xc = 0.f;
        for (int sdx = 0; sdx < DSPLIT; sdx++)
            xc += ws_xc[((size_t)sdx * BNUM + b) * KNUM + k];
        const float sc = ws_c2[k] - 2.f * xc;
        if (sc < best) { best = sc; bi = k; }   // strict: keeps lowest k per thread
    }
    svals[tid] = best; sidx[tid] = bi;
    __syncthreads();
    for (int off = 128; off > 0; off >>= 1) {
        if (tid < off) {
            const float ov = svals[tid + off];
            const int   oi = sidx[tid + off];
            if (ov < svals[tid] || (ov == svals[tid] && oi < sidx[tid])) {
                svals[tid] = ov; sidx[tid] = oi;
            }
        }
        __syncthreads();
    }
    if (tid == 0) {
        const int k = sidx[0];
        const float d2 = x2 + svals[0];
        out_mind[b] = sqrtf(fmaxf(d2, 0.f));
        out_idx[b]  = (float)k;   // harness reads whole d_out as fp32
        ws_idx[b]   = k;
    }
    if (tid < 64) out_usage[b * 64 + tid] = usage_in[b * 64 + tid];
}

// ---------------------------------------------------------------------------
// Kernel 3: gather quantized rows + usage scatter-add (after copy kernel).
// ---------------------------------------------------------------------------
__global__ __launch_bounds__(256) void gather_k(
    const float* __restrict__ codebook, const int* __restrict__ ws_idx,
    float* __restrict__ out_q, float* __restrict__ out_usage)
{
    const int b = blockIdx.x, tid = threadIdx.x;
    const int k = ws_idx[b];
    const float4* src = (const float4*)(codebook + (size_t)k * D);
    float4*       dst = (float4*)(out_q + (size_t)b * D);
    for (int i = tid; i < D / 4; i += 256) dst[i] = src[i];
    if (tid == 0) atomicAdd(out_usage + k, 1.0f);
}

extern "C" void kernel_launch(void* const* d_in, const int* in_sizes, int n_in,
                              void* d_out, int out_size, void* d_ws, size_t ws_size,
                              hipStream_t stream)
{
    const float* latent   = (const float*)d_in[0];
    const float* codebook = (const float*)d_in[1];
    const float* usage    = (const float*)d_in[2];

    float* out_q     = (float*)d_out;                       // 64*32000
    float* out_idx   = out_q + (size_t)BNUM * D;            // 64
    float* out_mind  = out_idx + BNUM;                      // 64
    float* out_usage = out_mind + BNUM;                     // 4096

    float* ws_xc  = (float*)d_ws;                           // DSPLIT*64*4096 fp32 (4 MB)
    float* ws_c2  = ws_xc + (size_t)DSPLIT * BNUM * KNUM;   // 4096 fp32
    int*   ws_idx = (int*)(ws_c2 + KNUM);                   // 64 int

    hipMemsetAsync(ws_c2, 0, KNUM * sizeof(float), stream);
    dist_gemm<<<dim3(KBLKS, DSPLIT), 256, 0, stream>>>(latent, codebook, ws_xc, ws_c2);
    argmin_k<<<BNUM, 256, 0, stream>>>(latent, ws_xc, ws_c2, usage,
                                       out_idx, out_mind, out_usage, ws_idx);
    gather_k<<<BNUM, 256, 0, stream>>>(codebook, ws_idx, out_q, out_usage);
}

// Round 2
// 766.032 us; speedup vs baseline: 1.1466x; 1.1466x over previous
//
#include <hip/hip_runtime.h>
#include <math.h>

#define D      32000
#define BNUM   64
#define KNUM   4096
#define TN     64      // codebook rows per block
#define BK     64      // d-elements staged per iteration
#define LDK    72      // LDS row stride in bf16 elems (144 B: 16B-aligned, breaks row-bank aliasing)

typedef __attribute__((ext_vector_type(8)))  short  short8;    // 8 bf16 = 4 VGPRs (MFMA A/B frag)
typedef __attribute__((ext_vector_type(16))) float  floatx16;  // 32x32 MFMA acc

__device__ __forceinline__ unsigned short f32_bf16_rne(float f) {
    unsigned u = __float_as_uint(f);
    u += 0x7fff + ((u >> 16) & 1);          // round-to-nearest-even
    return (unsigned short)(u >> 16);
}
__device__ __forceinline__ float bf16_f32(unsigned short h) {
    return __uint_as_float(((unsigned)h) << 16);
}

// ---------------------------------------------------------------------------
// xc[b][k] partials via bf16 hi/lo-split MFMA (3 products ~= fp32 exact),
// fused ||c||^2 (fp32, from pre-conversion values).
// Block: 256 thr = 4 waves, tile 64(B) x 64(K-rows); wave w -> 32x32 quadrant.
// blockIdx.x -> k0 = x*64 ; blockIdx.y -> d-range [y*dper, (y+1)*dper)
// ---------------------------------------------------------------------------
__global__ __launch_bounds__(256) void dist_mfma(
    const float* __restrict__ latent, const float* __restrict__ codebook,
    float* __restrict__ ws_xc, float* __restrict__ ws_c2, int dper)
{
    __shared__ __align__(16) unsigned short xs_hi[BNUM * LDK];
    __shared__ __align__(16) unsigned short xs_lo[BNUM * LDK];
    __shared__ __align__(16) unsigned short cs_hi[TN * LDK];
    __shared__ __align__(16) unsigned short cs_lo[TN * LDK];

    const int tid  = threadIdx.x;
    const int k0   = blockIdx.x * TN;
    const int d0b  = blockIdx.y * dper;
    const int nst  = dper / BK;

    // staging coords: pass p covers rows rbase+16p, cols col4*4..+3
    const int col4  = tid & 15;
    const int rbase = tid >> 4;
    const float* aptr = latent   + (size_t)rbase * D + d0b + col4 * 4;
    const float* bptr = codebook + (size_t)(k0 + rbase) * D + d0b + col4 * 4;

    // MFMA coords
    const int wave = tid >> 6, lane = tid & 63;
    const int lr = lane & 31, lh = lane >> 5;
    const int mh = (wave & 1) * 32;          // latent-row half
    const int nh = (wave >> 1) * 32;         // codebook-row half
    const int aoff = (mh + lr) * LDK + lh * 8;
    const int boff = (nh + lr) * LDK + lh * 8;

    floatx16 acc;
#pragma unroll
    for (int i = 0; i < 16; i++) acc[i] = 0.f;
    float c2p[4] = {0.f, 0.f, 0.f, 0.f};

    float4 pa[4], pb[4];
#pragma unroll
    for (int p = 0; p < 4; p++) {
        pa[p] = *(const float4*)(aptr + (size_t)(16 * p) * D);
        pb[p] = *(const float4*)(bptr + (size_t)(16 * p) * D);
    }

    for (int s = 0; s < nst; ++s) {
        // fused ||c||^2 from the fp32 values before conversion
#pragma unroll
        for (int p = 0; p < 4; p++)
            c2p[p] += pb[p].x * pb[p].x + pb[p].y * pb[p].y +
                      pb[p].z * pb[p].z + pb[p].w * pb[p].w;

        __syncthreads();  // previous MFMA phase done reading LDS
#pragma unroll
        for (int p = 0; p < 4; p++) {
            const int wo = (rbase + 16 * p) * LDK + col4 * 4;
            ushort4 h, l;
            h.x = f32_bf16_rne(pa[p].x); l.x = f32_bf16_rne(pa[p].x - bf16_f32(h.x));
            h.y = f32_bf16_rne(pa[p].y); l.y = f32_bf16_rne(pa[p].y - bf16_f32(h.y));
            h.z = f32_bf16_rne(pa[p].z); l.z = f32_bf16_rne(pa[p].z - bf16_f32(h.z));
            h.w = f32_bf16_rne(pa[p].w); l.w = f32_bf16_rne(pa[p].w - bf16_f32(h.w));
            *(ushort4*)(xs_hi + wo) = h;
            *(ushort4*)(xs_lo + wo) = l;
            h.x = f32_bf16_rne(pb[p].x); l.x = f32_bf16_rne(pb[p].x - bf16_f32(h.x));
            h.y = f32_bf16_rne(pb[p].y); l.y = f32_bf16_rne(pb[p].y - bf16_f32(h.y));
            h.z = f32_bf16_rne(pb[p].z); l.z = f32_bf16_rne(pb[p].z - bf16_f32(h.z));
            h.w = f32_bf16_rne(pb[p].w); l.w = f32_bf16_rne(pb[p].w - bf16_f32(h.w));
            *(ushort4*)(cs_hi + wo) = h;
            *(ushort4*)(cs_lo + wo) = l;
        }
        __syncthreads();

        // prefetch next chunk (overlaps with MFMA phase)
        if (s + 1 < nst) {
            const int doff = (s + 1) * BK;
#pragma unroll
            for (int p = 0; p < 4; p++) {
                pa[p] = *(const float4*)(aptr + (size_t)(16 * p) * D + doff);
                pb[p] = *(const float4*)(bptr + (size_t)(16 * p) * D + doff);
            }
        }

#pragma unroll
        for (int ks = 0; ks < 4; ++ks) {
            const short8 ah = *(const short8*)(xs_hi + aoff + ks * 16);
            const short8 al = *(const short8*)(xs_lo + aoff + ks * 16);
            const short8 bh = *(const short8*)(cs_hi + boff + ks * 16);
            const short8 bl = *(const short8*)(cs_lo + boff + ks * 16);
            acc = __builtin_amdgcn_mfma_f32_32x32x16_bf16(ah, bh, acc, 0, 0, 0);
            acc = __builtin_amdgcn_mfma_f32_32x32x16_bf16(ah, bl, acc, 0, 0, 0);
            acc = __builtin_amdgcn_mfma_f32_32x32x16_bf16(al, bh, acc, 0, 0, 0);
        }
    }

    // write xc partials: C/D layout col=lane&31, row=(reg&3)+8*(reg>>2)+4*(lane>>5)
    const int split = blockIdx.y;
#pragma unroll
    for (int r = 0; r < 16; ++r) {
        const int row = (r & 3) + 8 * (r >> 2) + 4 * lh;     // 0..31
        const int b = mh + row;
        ws_xc[((size_t)split * BNUM + b) * KNUM + (k0 + nh + lr)] = acc[r];
    }

    // reduce ||c||^2 partials over the 16 lanes sharing a row group
#pragma unroll
    for (int p = 0; p < 4; ++p) {
        float v = c2p[p];
        v += __shfl_xor(v, 1);
        v += __shfl_xor(v, 2);
        v += __shfl_xor(v, 4);
        v += __shfl_xor(v, 8);
        if ((lane & 15) == 0)
            atomicAdd(ws_c2 + k0 + rbase + 16 * p, v);
    }
}

// ---------------------------------------------------------------------------
// Per-b argmin over k; index/min-dist outputs; usage copy.
// ---------------------------------------------------------------------------
__global__ __launch_bounds__(256) void argmin_k(
    const float* __restrict__ latent, const float* __restrict__ ws_xc,
    const float* __restrict__ ws_c2, const float* __restrict__ usage_in,
    float* __restrict__ out_idx, float* __restrict__ out_mind,
    float* __restrict__ out_usage, int* __restrict__ ws_idx, int dsplit)
{
    const int b = blockIdx.x, tid = threadIdx.x;
    __shared__ float svals[256];
    __shared__ int   sidx[256];

    float s = 0.f;
    const float4* lf4 = (const float4*)(latent + (size_t)b * D);
    for (int i = tid; i < D / 4; i += 256) {
        const float4 v = lf4[i];
        s += v.x * v.x + v.y * v.y + v.z * v.z + v.w * v.w;
    }
    svals[tid] = s;
    __syncthreads();
    for (int off = 128; off > 0; off >>= 1) {
        if (tid < off) svals[tid] += svals[tid + off];
        __syncthreads();
    }
    const float x2 = svals[0];
    __syncthreads();

    float best = 3.402823466e38f;
    int   bi   = 0;
    for (int k = tid; k < KNUM; k += 256) {
        float xc = 0.f;
        for (int sdx = 0; sdx < dsplit; sdx++)
            xc += ws_xc[((size_t)sdx * BNUM + b) * KNUM + k];
        const float sc = ws_c2[k] - 2.f * xc;
        if (sc < best) { best = sc; bi = k; }
    }
    svals[tid] = best; sidx[tid] = bi;
    __syncthreads();
    for (int off = 128; off > 0; off >>= 1) {
        if (tid < off) {
            const float ov = svals[tid + off];
            const int   oi = sidx[tid + off];
            if (ov < svals[tid] || (ov == svals[tid] && oi < sidx[tid])) {
                svals[tid] = ov; sidx[tid] = oi;
            }
        }
        __syncthreads();
    }
    if (tid == 0) {
        const int k = sidx[0];
        out_mind[b] = sqrtf(fmaxf(x2 + svals[0], 0.f));
        out_idx[b]  = (float)k;
        ws_idx[b]   = k;
    }
    if (tid < 64) out_usage[b * 64 + tid] = usage_in[b * 64 + tid];
}

// ---------------------------------------------------------------------------
// Gather quantized rows (4 blocks per b) + usage scatter-add.
// ---------------------------------------------------------------------------
__global__ __launch_bounds__(256) void gather_k(
    const float* __restrict__ codebook, const int* __restrict__ ws_idx,
    float* __restrict__ out_q, float* __restrict__ out_usage)
{
    const int b = blockIdx.x, part = blockIdx.y, tid = threadIdx.x;
    const int k = ws_idx[b];
    const int n4 = D / 4 / 4;  // 2000 float4 per part
    const float4* src = (const float4*)(codebook + (size_t)k * D) + part * n4;
    float4*       dst = (float4*)(out_q + (size_t)b * D) + part * n4;
    for (int i = tid; i < n4; i += 256) dst[i] = src[i];
    if (part == 0 && tid == 0) atomicAdd(out_usage + k, 1.0f);
}

extern "C" void kernel_launch(void* const* d_in, const int* in_sizes, int n_in,
                              void* d_out, int out_size, void* d_ws, size_t ws_size,
                              hipStream_t stream)
{
    const float* latent   = (const float*)d_in[0];
    const float* codebook = (const float*)d_in[1];
    const float* usage    = (const float*)d_in[2];

    float* out_q     = (float*)d_out;                       // 64*32000
    float* out_idx   = out_q + (size_t)BNUM * D;            // 64
    float* out_mind  = out_idx + BNUM;                      // 64
    float* out_usage = out_mind + BNUM;                     // 4096

    // dsplit=10 -> 640 blocks, ws ~10.5 MB; fallback 4 (4.21 MB, proven fit)
    int dsplit = 10;
    if (ws_size < (size_t)dsplit * BNUM * KNUM * 4 + KNUM * 4 + 256) dsplit = 4;
    const int dper = D / dsplit;

    float* ws_xc  = (float*)d_ws;                           // dsplit*64*4096 fp32
    float* ws_c2  = ws_xc + (size_t)dsplit * BNUM * KNUM;   // 4096 fp32
    int*   ws_idx = (int*)(ws_c2 + KNUM);                   // 64 int

    hipMemsetAsync(ws_c2, 0, KNUM * sizeof(float), stream);
    dist_mfma<<<dim3(KNUM / TN, dsplit), 256, 0, stream>>>(latent, codebook, ws_xc, ws_c2, dper);
    argmin_k<<<BNUM, 256, 0, stream>>>(latent, ws_xc, ws_c2, usage,
                                       out_idx, out_mind, out_usage, ws_idx, dsplit);
    gather_k<<<dim3(BNUM, 4), 256, 0, stream>>>(codebook, ws_idx, out_q, out_usage);
}

// Round 3
// 756.327 us; speedup vs baseline: 1.1613x; 1.0128x over previous
//
#include <hip/hip_runtime.h>
#include <math.h>

#define D      32000
#define BNUM   64
#define KNUM   4096
#define TN     64      // codebook rows per block
#define BK     64      // d-elements staged per iteration
#define LDK    72      // LDS row stride in bf16 elems (144 B, 16B-aligned rows)

typedef __attribute__((ext_vector_type(8)))  short  short8;    // 8 bf16 (MFMA A/B frag)
typedef __attribute__((ext_vector_type(16))) float  floatx16;  // 32x32 MFMA acc

__device__ __forceinline__ unsigned short f32_bf16_rne(float f) {
    unsigned u = __float_as_uint(f);
    u += 0x7fff + ((u >> 16) & 1);          // round-to-nearest-even
    return (unsigned short)(u >> 16);
}
__device__ __forceinline__ float bf16_f32(unsigned short h) {
    return __uint_as_float(((unsigned)h) << 16);
}
__device__ __forceinline__ void cvt_hl(const float4 v, ushort4* h, ushort4* l) {
    h->x = f32_bf16_rne(v.x); l->x = f32_bf16_rne(v.x - bf16_f32(h->x));
    h->y = f32_bf16_rne(v.y); l->y = f32_bf16_rne(v.y - bf16_f32(h->y));
    h->z = f32_bf16_rne(v.z); l->z = f32_bf16_rne(v.z - bf16_f32(h->z));
    h->w = f32_bf16_rne(v.w); l->w = f32_bf16_rne(v.w - bf16_f32(h->w));
}

// CK-style barriers: no vmcnt(0) drain -> global prefetches survive the barrier.
__device__ __forceinline__ void barrier_arrive() {        // pure arrival sync
    __builtin_amdgcn_s_barrier();
}
__device__ __forceinline__ void barrier_lds() {           // LDS writes visible
    __builtin_amdgcn_s_waitcnt(0xc07f);                   // lgkmcnt(0) only
    __builtin_amdgcn_s_barrier();
}

// ---------------------------------------------------------------------------
// xc[b][k] partials via bf16 hi/lo-split MFMA (3 products ~= fp32 exact),
// fused ||c||^2. Block: 4 waves, tile 64(B) x 64(K); wave -> 32x32 quadrant.
// 2-deep codebook register prefetch + raw barriers keep HBM stream saturated.
// ---------------------------------------------------------------------------
__global__ __launch_bounds__(256, 4) void dist_mfma(
    const float* __restrict__ latent, const float* __restrict__ codebook,
    float* __restrict__ ws_xc, float* __restrict__ ws_c2, int dper)
{
    __shared__ __align__(16) unsigned short xs_hi[BNUM * LDK];
    __shared__ __align__(16) unsigned short xs_lo[BNUM * LDK];
    __shared__ __align__(16) unsigned short cs_hi[TN * LDK];
    __shared__ __align__(16) unsigned short cs_lo[TN * LDK];

    const int tid  = threadIdx.x;
    const int k0   = blockIdx.x * TN;
    const int d0b  = blockIdx.y * dper;
    const int nst  = dper / BK;

    // staging coords: pass p covers row rbase+16p, 4 floats at col4*4
    const int col4  = tid & 15;
    const int rbase = tid >> 4;
    const float* aptr = latent   + (size_t)rbase * D + d0b + col4 * 4;
    const float* bptr = codebook + (size_t)(k0 + rbase) * D + d0b + col4 * 4;

    // MFMA coords
    const int wave = tid >> 6, lane = tid & 63;
    const int lr = lane & 31, lh = lane >> 5;
    const int mh = (wave & 1) * 32;
    const int nh = (wave >> 1) * 32;
    const int aoff = (mh + lr) * LDK + lh * 8;
    const int boff = (nh + lr) * LDK + lh * 8;

    floatx16 acc;
#pragma unroll
    for (int i = 0; i < 16; i++) acc[i] = 0.f;
    float c2p[4] = {0.f, 0.f, 0.f, 0.f};

    float4 pa[4], pbA[4], pbB[4];

#define LOADA(DST, S)                                                          \
    if ((S) < nst) {                                                           \
        const size_t _o = (size_t)(S) * BK;                                    \
        _Pragma("unroll")                                                      \
        for (int p = 0; p < 4; p++)                                            \
            DST[p] = *(const float4*)(aptr + (size_t)(16 * p) * D + _o);       \
    }
#define LOADB(DST, S)                                                          \
    if ((S) < nst) {                                                           \
        const size_t _o = (size_t)(S) * BK;                                    \
        _Pragma("unroll")                                                      \
        for (int p = 0; p < 4; p++)                                            \
            DST[p] = *(const float4*)(bptr + (size_t)(16 * p) * D + _o);       \
    }

#define STAGE(PBC, S)                                                          \
    {                                                                          \
        _Pragma("unroll")                                                      \
        for (int p = 0; p < 4; p++)                                            \
            c2p[p] += PBC[p].x * PBC[p].x + PBC[p].y * PBC[p].y +              \
                      PBC[p].z * PBC[p].z + PBC[p].w * PBC[p].w;               \
        barrier_arrive();  /* prior MFMA done reading LDS */                   \
        _Pragma("unroll")                                                      \
        for (int p = 0; p < 4; p++) {                                          \
            const int wo = (rbase + 16 * p) * LDK + col4 * 4;                  \
            ushort4 h, l;                                                      \
            cvt_hl(pa[p], &h, &l);                                             \
            *(ushort4*)(xs_hi + wo) = h;                                       \
            *(ushort4*)(xs_lo + wo) = l;                                       \
            cvt_hl(PBC[p], &h, &l);                                            \
            *(ushort4*)(cs_hi + wo) = h;                                       \
            *(ushort4*)(cs_lo + wo) = l;                                       \
        }                                                                      \
        LOADA(pa, (S) + 1);   /* latent s+1 (issued first: waited first) */    \
        LOADB(PBC, (S) + 2);  /* codebook s+2 stays in flight 2 stages */      \
        barrier_lds();                                                         \
        _Pragma("unroll")                                                      \
        for (int ks = 0; ks < 4; ++ks) {                                       \
            const short8 ah = *(const short8*)(xs_hi + aoff + ks * 16);        \
            const short8 al = *(const short8*)(xs_lo + aoff + ks * 16);        \
            const short8 bh = *(const short8*)(cs_hi + boff + ks * 16);        \
            const short8 bl = *(const short8*)(cs_lo + boff + ks * 16);        \
            acc = __builtin_amdgcn_mfma_f32_32x32x16_bf16(ah, bh, acc, 0,0,0); \
            acc = __builtin_amdgcn_mfma_f32_32x32x16_bf16(ah, bl, acc, 0,0,0); \
            acc = __builtin_amdgcn_mfma_f32_32x32x16_bf16(al, bh, acc, 0,0,0); \
        }                                                                      \
    }

    LOADA(pa, 0);
    LOADB(pbA, 0);
    LOADB(pbB, 1);

    int s = 0;
    for (; s + 1 < nst; s += 2) {
        STAGE(pbA, s);
        STAGE(pbB, s + 1);
    }
    if (s < nst) STAGE(pbA, s);

#undef STAGE
#undef LOADA
#undef LOADB

    // write xc partials: C/D layout col=lane&31, row=(reg&3)+8*(reg>>2)+4*(lane>>5)
    const int split = blockIdx.y;
#pragma unroll
    for (int r = 0; r < 16; ++r) {
        const int row = (r & 3) + 8 * (r >> 2) + 4 * lh;
        const int b = mh + row;
        ws_xc[((size_t)split * BNUM + b) * KNUM + (k0 + nh + lr)] = acc[r];
    }

    // reduce ||c||^2 partials over the 16 lanes sharing a row group
#pragma unroll
    for (int p = 0; p < 4; ++p) {
        float v = c2p[p];
        v += __shfl_xor(v, 1);
        v += __shfl_xor(v, 2);
        v += __shfl_xor(v, 4);
        v += __shfl_xor(v, 8);
        if ((lane & 15) == 0)
            atomicAdd(ws_c2 + k0 + rbase + 16 * p, v);
    }
}

// ---------------------------------------------------------------------------
// Partial argmin: block (b, kc) scans k in [kc*1024, (kc+1)*1024).
// ---------------------------------------------------------------------------
__global__ __launch_bounds__(256) void argmin_part(
    const float* __restrict__ ws_xc, const float* __restrict__ ws_c2,
    float* __restrict__ ws_bscore, int* __restrict__ ws_bidx, int dsplit)
{
    const int b = blockIdx.x, kc = blockIdx.y, tid = threadIdx.x;
    __shared__ float sv[256];
    __shared__ int   si[256];

    float best = 3.402823466e38f;
    int   bi   = 0;
    for (int k = kc * 1024 + tid; k < (kc + 1) * 1024; k += 256) {
        float xc = 0.f;
        for (int s = 0; s < dsplit; s++)
            xc += ws_xc[((size_t)s * BNUM + b) * KNUM + k];
        const float sc = ws_c2[k] - 2.f * xc;
        if (sc < best) { best = sc; bi = k; }   // strict: lowest k per thread
    }
    sv[tid] = best; si[tid] = bi;
    __syncthreads();
    for (int off = 128; off > 0; off >>= 1) {
        if (tid < off) {
            const float ov = sv[tid + off];
            const int   oi = si[tid + off];
            if (ov < sv[tid] || (ov == sv[tid] && oi < si[tid])) {
                sv[tid] = ov; si[tid] = oi;
            }
        }
        __syncthreads();
    }
    if (tid == 0) { ws_bscore[b * 4 + kc] = sv[0]; ws_bidx[b * 4 + kc] = si[0]; }
}

// ---------------------------------------------------------------------------
// Finalize: ||x_b||^2, pick best of 4 chunks, outputs, usage copy.
// ---------------------------------------------------------------------------
__global__ __launch_bounds__(256) void finalize_k(
    const float* __restrict__ latent, const float* __restrict__ ws_bscore,
    const int* __restrict__ ws_bidx, const float* __restrict__ usage_in,
    float* __restrict__ out_idx, float* __restrict__ out_mind,
    float* __restrict__ out_usage, int* __restrict__ ws_idx)
{
    const int b = blockIdx.x, tid = threadIdx.x;
    __shared__ float sv[256];

    float s = 0.f;
    const float4* lf4 = (const float4*)(latent + (size_t)b * D);
    for (int i = tid; i < D / 4; i += 256) {
        const float4 v = lf4[i];
        s += v.x * v.x + v.y * v.y + v.z * v.z + v.w * v.w;
    }
    sv[tid] = s;
    __syncthreads();
    for (int off = 128; off > 0; off >>= 1) {
        if (tid < off) sv[tid] += sv[tid + off];
        __syncthreads();
    }
    if (tid == 0) {
        const float x2 = sv[0];
        float best = ws_bscore[b * 4];
        int   bi   = ws_bidx[b * 4];
        for (int kc = 1; kc < 4; kc++) {
            const float v = ws_bscore[b * 4 + kc];
            if (v < best) { best = v; bi = ws_bidx[b * 4 + kc]; }  // ties -> lower kc
        }
        out_mind[b] = sqrtf(fmaxf(x2 + best, 0.f));
        out_idx[b]  = (float)bi;
        ws_idx[b]   = bi;
    }
    if (tid < 64) out_usage[b * 64 + tid] = usage_in[b * 64 + tid];
}

// ---------------------------------------------------------------------------
// Gather quantized rows (4 blocks per b) + usage scatter-add.
// ---------------------------------------------------------------------------
__global__ __launch_bounds__(256) void gather_k(
    const float* __restrict__ codebook, const int* __restrict__ ws_idx,
    float* __restrict__ out_q, float* __restrict__ out_usage)
{
    const int b = blockIdx.x, part = blockIdx.y, tid = threadIdx.x;
    const int k = ws_idx[b];
    const int n4 = D / 4 / 4;  // 2000 float4 per part
    const float4* src = (const float4*)(codebook + (size_t)k * D) + part * n4;
    float4*       dst = (float4*)(out_q + (size_t)b * D) + part * n4;
    for (int i = tid; i < n4; i += 256) dst[i] = src[i];
    if (part == 0 && tid == 0) atomicAdd(out_usage + k, 1.0f);
}

extern "C" void kernel_launch(void* const* d_in, const int* in_sizes, int n_in,
                              void* d_out, int out_size, void* d_ws, size_t ws_size,
                              hipStream_t stream)
{
    const float* latent   = (const float*)d_in[0];
    const float* codebook = (const float*)d_in[1];
    const float* usage    = (const float*)d_in[2];

    float* out_q     = (float*)d_out;                       // 64*32000
    float* out_idx   = out_q + (size_t)BNUM * D;            // 64
    float* out_mind  = out_idx + BNUM;                      // 64
    float* out_usage = out_mind + BNUM;                     // 4096

    // dsplit=20 -> 1280 blocks (~4 blocks/CU); ws ~21 MB. Fallback 4 (4.2 MB).
    int dsplit = 20;
    if (ws_size < ((size_t)dsplit * BNUM * KNUM + KNUM + 4 * BNUM * 2 + BNUM) * 4 + 256)
        dsplit = 4;
    const int dper = D / dsplit;

    float* ws_xc     = (float*)d_ws;                            // dsplit*64*4096 f32
    float* ws_c2     = ws_xc + (size_t)dsplit * BNUM * KNUM;    // 4096 f32
    float* ws_bscore = ws_c2 + KNUM;                            // 256 f32
    int*   ws_bidx   = (int*)(ws_bscore + 4 * BNUM);            // 256 int
    int*   ws_idx    = ws_bidx + 4 * BNUM;                      // 64 int

    hipMemsetAsync(ws_c2, 0, KNUM * sizeof(float), stream);
    dist_mfma<<<dim3(KNUM / TN, dsplit), 256, 0, stream>>>(latent, codebook, ws_xc, ws_c2, dper);
    argmin_part<<<dim3(BNUM, 4), 256, 0, stream>>>(ws_xc, ws_c2, ws_bscore, ws_bidx, dsplit);
    finalize_k<<<BNUM, 256, 0, stream>>>(latent, ws_bscore, ws_bidx, usage,
                                         out_idx, out_mind, out_usage, ws_idx);
    gather_k<<<dim3(BNUM, 4), 256, 0, stream>>>(codebook, ws_idx, out_q, out_usage);
}